// Round 6
// baseline (329.371 us; speedup 1.0000x reference)
//
#include <hip/hip_runtime.h>
#include <math.h>

// Problem constants: B=32, O=4096, F=256, H=8, HID=128
#define MB_ 131072
#define F_  256
#define HID_ 128
#define H_  8
#define O_  4096
#define B_  32

typedef __attribute__((ext_vector_type(8))) short short8;
typedef __attribute__((ext_vector_type(4))) float f32x4;

static __device__ __forceinline__ unsigned short f2bf(float f) {
    unsigned int u = __float_as_uint(f);
    unsigned int r = (u + 0x7fffu + ((u >> 16) & 1u)) >> 16;  // RNE
    return (unsigned short)r;
}
static __device__ __forceinline__ float bflo(unsigned int u) {
    return __uint_as_float(u << 16);
}
static __device__ __forceinline__ float bfhi(unsigned int u) {
    return __uint_as_float(u & 0xffff0000u);
}
// order-preserving float->uint key for atomicMax
static __device__ __forceinline__ unsigned int fkey(float f) {
    unsigned int u = __float_as_uint(f);
    return (u & 0x80000000u) ? ~u : (u | 0x80000000u);
}
// pack 8 f32 (two float4) -> short8 bf16
static __device__ __forceinline__ short8 pack_bf16x8(const float4 a, const float4 b) {
    short8 r;
    r[0] = (short)f2bf(a.x); r[1] = (short)f2bf(a.y);
    r[2] = (short)f2bf(a.z); r[3] = (short)f2bf(a.w);
    r[4] = (short)f2bf(b.x); r[5] = (short)f2bf(b.y);
    r[6] = (short)f2bf(b.z); r[7] = (short)f2bf(b.w);
    return r;
}
// raw barrier: waits only LDS ops of this wave, does NOT drain vmcnt
static __device__ __forceinline__ void sync_lds() {
    asm volatile("s_waitcnt lgkmcnt(0)" ::: "memory");
    __builtin_amdgcn_s_barrier();
    __builtin_amdgcn_sched_barrier(0);
}

// ---------------- Prep: transpose + bf16-cast weights, init Mmax ------------
__global__ __launch_bounds__(256) void k_prep(
    const float* __restrict__ W_in, const float* __restrict__ W_blk,
    unsigned short* __restrict__ WinT, unsigned short* __restrict__ WblkT,
    unsigned int* __restrict__ Mmax)
{
    const int idx = blockIdx.x * 256 + threadIdx.x;
    if (idx < 256) Mmax[idx] = 0u;  // key-space -inf
    if (idx < 32768) {
        const int n = idx >> 8, k = idx & 255;
        WinT[idx] = f2bf(W_in[(size_t)k * HID_ + n]);
    } else {
        const int i2 = idx - 32768;  // < 16384
        const int n = i2 >> 7, k = i2 & 127;
        WblkT[i2] = f2bf(W_blk[(size_t)k * HID_ + n]);
    }
}

// ---------------- Fused GEMM1+GEMM2 -----------------------------------------
// GEMM1 BK=64, 4 K-steps. Per iteration (vmcnt-FIFO-safe order):
//   1) issue B(kt) frag loads (L2)      <- FIRST, so MFMA's wait on them
//   2) issue x(kt+1) tile loads (HBM)      does NOT drain the x prefetch
//   3) stage x(kt) -> LDS (waits only oldest = x(kt))
//   4) lgkmcnt+barrier (non-draining), ds_read frags, 16 MFMA
// LDS 32768 B: stg[2][128][64] bf16 (chunk-XOR swizzle) union h_s[128][128].
__global__ __launch_bounds__(512, 4) void k_fused(
    const float* __restrict__ x, const unsigned short* __restrict__ WinT,
    const float* __restrict__ b_in,
    const unsigned short* __restrict__ WblkT, const float* __restrict__ b_blk,
    unsigned short* __restrict__ h_out, unsigned short* __restrict__ z_out,
    float* __restrict__ mask_out,
    float* __restrict__ sumP, float* __restrict__ sumsqP)
{
    __shared__ unsigned short smem[16384];   // 32768 B
    unsigned short* stg = smem;              // [2][128][64] bf16, swizzled
    unsigned short* h_s = smem;              // [128][128] bf16, swizzled

    const int tid = threadIdx.x;
    const int R0 = blockIdx.x * 128;
    const int wave = tid >> 6;   // 0..7
    const int wrow = wave >> 2;  // 0..1
    const int wcol = wave & 3;   // 0..3
    const int lane = tid & 63;
    const int lm = lane & 15, quad = lane >> 4;

    // staging role: row srow, 16 cols at sc*16 within each 64-col K-tile
    const int srow = tid >> 2, sc = tid & 3;
    const float* xb = x + (size_t)(R0 + srow) * F_ + sc * 16;
    const int ss = srow & 7;
    const int wo0 = srow * 64 + (((2 * sc) ^ ss) << 3);      // ushort units
    const int wo1 = srow * 64 + (((2 * sc + 1) ^ ss) << 3);

    // A-frag LDS offsets (swizzled): row ar, k-slice ks -> chunk (ks*4+quad)^(ar&7)
    int aoff[4][2];
#pragma unroll
    for (int mi = 0; mi < 4; mi++) {
        const int ar = wrow * 64 + mi * 16 + lm;
#pragma unroll
        for (int ks = 0; ks < 2; ks++)
            aoff[mi][ks] = ar * 64 + ((((ks * 4 + quad) ^ (ar & 7))) << 3);
    }
    // GEMM1 B-frag global pointers (WinT, L2-hot)
    const unsigned short* wr0 = WinT + (size_t)(wcol * 32 + lm) * F_ + quad * 8;
    const unsigned short* wr1 = wr0 + (size_t)16 * F_;

    f32x4 acc[4][2];
#pragma unroll
    for (int i = 0; i < 4; i++)
#pragma unroll
        for (int j = 0; j < 2; j++) acc[i][j] = (f32x4){0.f, 0.f, 0.f, 0.f};
    float msq = 0.f;

    // prologue: x tile 0 (issued before any B load -> oldest in FIFO)
    float4 xC[4], xN[4];
#pragma unroll
    for (int q = 0; q < 4; q++) xC[q] = *(const float4*)(xb + q * 4);

    // ---- GEMM1: 4 K-steps of 64 ----
#pragma unroll
    for (int kt = 0; kt < 4; kt++) {
        // 1) issue B(kt) frags (before x prefetch! -> MFMA wait won't drain x)
        short8 bC[2][2];
#pragma unroll
        for (int ks = 0; ks < 2; ks++) {
            bC[ks][0] = *(const short8*)(wr0 + kt * 64 + ks * 32);
            bC[ks][1] = *(const short8*)(wr1 + kt * 64 + ks * 32);
        }
        // 2) issue x(kt+1)
        if (kt < 3) {
#pragma unroll
            for (int q = 0; q < 4; q++)
                xN[q] = *(const float4*)(xb + (kt + 1) * 64 + q * 4);
        }
        __builtin_amdgcn_sched_barrier(0);
        // 3) stage tile kt (waits only x(kt) = oldest outstanding)
#pragma unroll
        for (int q = 0; q < 4; q++) {
            const float4 v = xC[q];
            msq += v.x * v.x + v.y * v.y + v.z * v.z + v.w * v.w;
        }
        *(short8*)(stg + (kt & 1) * 8192 + wo0) = pack_bf16x8(xC[0], xC[1]);
        *(short8*)(stg + (kt & 1) * 8192 + wo1) = pack_bf16x8(xC[2], xC[3]);
        // 4) publish + consume
        sync_lds();
        short8 af[4][2];
#pragma unroll
        for (int mi = 0; mi < 4; mi++)
#pragma unroll
            for (int ks = 0; ks < 2; ks++)
                af[mi][ks] = *(const short8*)(stg + (kt & 1) * 8192 + aoff[mi][ks]);
#pragma unroll
        for (int ks = 0; ks < 2; ks++)
#pragma unroll
            for (int mi = 0; mi < 4; mi++)
#pragma unroll
                for (int ni = 0; ni < 2; ni++)
                    acc[mi][ni] = __builtin_amdgcn_mfma_f32_16x16x32_bf16(af[mi][ks], bC[ks][ni], acc[mi][ni], 0, 0, 0);
        if (kt < 3) {
#pragma unroll
            for (int q = 0; q < 4; q++) xC[q] = xN[q];
        }
    }

    // mask: reduce sumsq over the 4 col-chunks of each row (lanes t^1, t^2)
    msq += __shfl_xor(msq, 1, 64);
    msq += __shfl_xor(msq, 2, 64);
    if ((tid & 3) == 0) mask_out[R0 + srow] = (msq != 0.f) ? 1.f : 0.f;

    __syncthreads();   // all stg reads done before h_s overwrite

    // ---- epilogue 1: bias + relu -> h_s (swizzled) ----
    {
        float bcol[2];
#pragma unroll
        for (int ni = 0; ni < 2; ni++) bcol[ni] = b_in[wcol * 32 + ni * 16 + lm];
#pragma unroll
        for (int mi = 0; mi < 4; mi++)
#pragma unroll
            for (int r = 0; r < 4; r++) {
                const int rl = wrow * 64 + mi * 16 + quad * 4 + r;
#pragma unroll
                for (int ni = 0; ni < 2; ni++) {
                    const int col = wcol * 32 + ni * 16 + lm;
                    const float v = fmaxf(acc[mi][ni][r] + bcol[ni], 0.f);
                    h_s[rl * 128 + ((((col >> 3) ^ (rl & 7)) << 3) | (col & 7))] = f2bf(v);
                }
            }
    }
#pragma unroll
    for (int i = 0; i < 4; i++)
#pragma unroll
        for (int j = 0; j < 2; j++) acc[i][j] = (f32x4){0.f, 0.f, 0.f, 0.f};
    __syncthreads();   // h_s complete

    // ---- coalesced h_out stores from h_s (16B, fire-and-forget) ----
    {
        const int crow = tid >> 2, cb = tid & 3;
#pragma unroll
        for (int j = 0; j < 4; j++) {
            const int ch = cb * 4 + j;
            const short8 v = *(const short8*)(h_s + crow * 128 + ((ch ^ (crow & 7)) << 3));
            *(short8*)(h_out + (size_t)(R0 + crow) * HID_ + ch * 8) = v;
        }
    }

    // ---- GEMM2: A from h_s, B from WblkT (L2) ----
    {
        const unsigned short* wb0 = WblkT + (size_t)(wcol * 32 + lm) * HID_ + quad * 8;
        const unsigned short* wb1 = wb0 + (size_t)16 * HID_;
#pragma unroll
        for (int kt2 = 0; kt2 < 4; kt2++) {
            short8 wbf[2];
            wbf[0] = *(const short8*)(wb0 + kt2 * 32);
            wbf[1] = *(const short8*)(wb1 + kt2 * 32);
            short8 haf[4];
#pragma unroll
            for (int mi = 0; mi < 4; mi++) {
                const int hr = wrow * 64 + mi * 16 + lm;
                haf[mi] = *(const short8*)(h_s + hr * 128 + (((kt2 * 4 + quad) ^ (hr & 7)) << 3));
            }
#pragma unroll
            for (int mi = 0; mi < 4; mi++)
#pragma unroll
                for (int ni = 0; ni < 2; ni++)
                    acc[mi][ni] = __builtin_amdgcn_mfma_f32_16x16x32_bf16(haf[mi], wbf[ni], acc[mi][ni], 0, 0, 0);
        }
    }

    __syncthreads();   // all GEMM2 h_s reads done before z overwrite

    // ---- epilogue 2: bias, z -> h_s, BN partials via shfl ----
    {
        float bcol2[2];
#pragma unroll
        for (int ni = 0; ni < 2; ni++) bcol2[ni] = b_blk[wcol * 32 + ni * 16 + lm];
        float s_c[2] = {0.f, 0.f}, ss_c[2] = {0.f, 0.f};
#pragma unroll
        for (int mi = 0; mi < 4; mi++)
#pragma unroll
            for (int r = 0; r < 4; r++) {
                const int rl = wrow * 64 + mi * 16 + quad * 4 + r;
#pragma unroll
                for (int ni = 0; ni < 2; ni++) {
                    const int col = wcol * 32 + ni * 16 + lm;
                    const float zv = acc[mi][ni][r] + bcol2[ni];
                    s_c[ni] += zv;
                    ss_c[ni] += zv * zv;
                    h_s[rl * 128 + ((((col >> 3) ^ (rl & 7)) << 3) | (col & 7))] = f2bf(zv);
                }
            }
        // reduce over quad (rows) -> quad==0 lanes hold col sums for this wrow half
#pragma unroll
        for (int ni = 0; ni < 2; ni++) {
            s_c[ni]  += __shfl_xor(s_c[ni], 16, 64);
            s_c[ni]  += __shfl_xor(s_c[ni], 32, 64);
            ss_c[ni] += __shfl_xor(ss_c[ni], 16, 64);
            ss_c[ni] += __shfl_xor(ss_c[ni], 32, 64);
        }
        if (quad == 0) {
#pragma unroll
            for (int ni = 0; ni < 2; ni++) {
                const int col = wcol * 32 + ni * 16 + lm;
                sumP[((size_t)blockIdx.x * 2 + wrow) * 128 + col]   = s_c[ni];
                sumsqP[((size_t)blockIdx.x * 2 + wrow) * 128 + col] = ss_c[ni];
            }
        }
    }
    __syncthreads();   // z tile complete

    // ---- coalesced z_out stores ----
    {
        const int crow = tid >> 2, cb = tid & 3;
#pragma unroll
        for (int j = 0; j < 4; j++) {
            const int ch = cb * 4 + j;
            const short8 v = *(const short8*)(h_s + crow * 128 + ((ch ^ (crow & 7)) << 3));
            *(short8*)(z_out + (size_t)(R0 + crow) * HID_ + ch * 8) = v;
        }
    }
}

// ---------------- BN finalize (2048 partials) -------------------------------
__global__ __launch_bounds__(256) void k_bnfin(
    const float* __restrict__ sumP, const float* __restrict__ sumsqP,
    const float* __restrict__ gamma, const float* __restrict__ beta,
    float* __restrict__ scale, float* __restrict__ shift)
{
    const int c = blockIdx.x;
    const int tid = threadIdx.x;
    float s = 0.f, ss = 0.f;
    for (int i = tid; i < 2048; i += 256) {
        s  += sumP[(size_t)i * 128 + c];
        ss += sumsqP[(size_t)i * 128 + c];
    }
#pragma unroll
    for (int off = 32; off; off >>= 1) {
        s  += __shfl_xor(s, off, 64);
        ss += __shfl_xor(ss, off, 64);
    }
    __shared__ float rs[4], rss[4];
    const int wid = tid >> 6, lane = tid & 63;
    if (lane == 0) { rs[wid] = s; rss[wid] = ss; }
    __syncthreads();
    if (tid == 0) {
        const float S  = rs[0] + rs[1] + rs[2] + rs[3];
        const float SS = rss[0] + rss[1] + rss[2] + rss[3];
        const float inv_m = 1.0f / (float)MB_;
        const float mu = S * inv_m;
        const float var = SS * inv_m - mu * mu;
        const float sc = gamma[c] * rsqrtf(var + 1e-5f);
        scale[c] = sc;
        shift[c] = beta[c] - mu * sc;
    }
}

// ---------------- logits + gumbel + per-(b,h) max ---------------------------
__global__ __launch_bounds__(256) void k_logits(
    const unsigned short* __restrict__ h_in, const unsigned short* __restrict__ z_in,
    const float* __restrict__ scale, const float* __restrict__ shift,
    const float* __restrict__ W_fc, const float* __restrict__ b_fc,
    const float* __restrict__ mask, const float* __restrict__ gumbel,
    float* __restrict__ t_out, unsigned int* __restrict__ Mmax)
{
    __shared__ float wfc_s[1024];
    __shared__ float sc_s[128], sh_s[128];
    const int tid = threadIdx.x;
    for (int i = tid; i < 1024; i += 256) wfc_s[i] = W_fc[i];
    if (tid < 128) { sc_s[tid] = scale[tid]; sh_s[tid] = shift[tid]; }
    __syncthreads();

    const size_t row0 = (size_t)blockIdx.x * 512 + tid;
    const size_t row1 = row0 + 256;
    float a0[8], a1[8];
#pragma unroll
    for (int j = 0; j < 8; j++) { a0[j] = 0.f; a1[j] = 0.f; }

    const uint4* hp0 = (const uint4*)(h_in + row0 * HID_);
    const uint4* zq0 = (const uint4*)(z_in + row0 * HID_);
    const uint4* hp1 = (const uint4*)(h_in + row1 * HID_);
    const uint4* zq1 = (const uint4*)(z_in + row1 * HID_);

#pragma unroll 2
    for (int kc = 0; kc < 16; kc++) {
        const uint4 h0 = hp0[kc], z0 = zq0[kc];
        const uint4 h1 = hp1[kc], z1 = zq1[kc];
        const unsigned int hs0[4] = {h0.x, h0.y, h0.z, h0.w};
        const unsigned int zs0[4] = {z0.x, z0.y, z0.z, z0.w};
        const unsigned int hs1[4] = {h1.x, h1.y, h1.z, h1.w};
        const unsigned int zs1[4] = {z1.x, z1.y, z1.z, z1.w};
#pragma unroll
        for (int p = 0; p < 4; p++) {
            const int k = kc * 8 + p * 2;
            const float sck0 = sc_s[k], shk0 = sh_s[k];
            const float sck1 = sc_s[k + 1], shk1 = sh_s[k + 1];
            const float4 wA = *(const float4*)&wfc_s[k * 8];
            const float4 wB = *(const float4*)&wfc_s[k * 8 + 4];
            const float4 wC = *(const float4*)&wfc_s[k * 8 + 8];
            const float4 wD = *(const float4*)&wfc_s[k * 8 + 12];
            {
                const float hf0 = bflo(hs0[p]), hf1 = bfhi(hs0[p]);
                const float zf0 = bflo(zs0[p]), zf1 = bfhi(zs0[p]);
                const float hb0 = fmaxf(zf0 * sck0 + shk0, 0.f) + hf0;
                const float hb1 = fmaxf(zf1 * sck1 + shk1, 0.f) + hf1;
                a0[0] += hb0 * wA.x + hb1 * wC.x;  a0[1] += hb0 * wA.y + hb1 * wC.y;
                a0[2] += hb0 * wA.z + hb1 * wC.z;  a0[3] += hb0 * wA.w + hb1 * wC.w;
                a0[4] += hb0 * wB.x + hb1 * wD.x;  a0[5] += hb0 * wB.y + hb1 * wD.y;
                a0[6] += hb0 * wB.z + hb1 * wD.z;  a0[7] += hb0 * wB.w + hb1 * wD.w;
            }
            {
                const float hf0 = bflo(hs1[p]), hf1 = bfhi(hs1[p]);
                const float zf0 = bflo(zs1[p]), zf1 = bfhi(zs1[p]);
                const float hb0 = fmaxf(zf0 * sck0 + shk0, 0.f) + hf0;
                const float hb1 = fmaxf(zf1 * sck1 + shk1, 0.f) + hf1;
                a1[0] += hb0 * wA.x + hb1 * wC.x;  a1[1] += hb0 * wA.y + hb1 * wC.y;
                a1[2] += hb0 * wA.z + hb1 * wC.z;  a1[3] += hb0 * wA.w + hb1 * wC.w;
                a1[4] += hb0 * wB.x + hb1 * wD.x;  a1[5] += hb0 * wB.y + hb1 * wD.y;
                a1[6] += hb0 * wB.z + hb1 * wD.z;  a1[7] += hb0 * wB.w + hb1 * wD.w;
            }
        }
    }

    float bf[8];
#pragma unroll
    for (int j = 0; j < 8; j++) bf[j] = b_fc[j];
    const float mk0 = mask[row0], mk1 = mask[row1];
    float g0[8], g1[8];
    *(float4*)&g0[0] = *(const float4*)(gumbel + row0 * 8);
    *(float4*)&g0[4] = *(const float4*)(gumbel + row0 * 8 + 4);
    *(float4*)&g1[0] = *(const float4*)(gumbel + row1 * 8);
    *(float4*)&g1[4] = *(const float4*)(gumbel + row1 * 8 + 4);
    float t0[8], t1[8];
#pragma unroll
    for (int j = 0; j < 8; j++) {
        t0[j] = (a0[j] + bf[j]) * mk0 + g0[j];
        t1[j] = (a1[j] + bf[j]) * mk1 + g1[j];
    }
    *(float4*)(t_out + row0 * 8)     = *(float4*)&t0[0];
    *(float4*)(t_out + row0 * 8 + 4) = *(float4*)&t0[4];
    *(float4*)(t_out + row1 * 8)     = *(float4*)&t1[0];
    *(float4*)(t_out + row1 * 8 + 4) = *(float4*)&t1[4];

    float tm[8];
#pragma unroll
    for (int j = 0; j < 8; j++) tm[j] = fmaxf(t0[j], t1[j]);
#pragma unroll
    for (int off = 32; off; off >>= 1)
#pragma unroll
        for (int j = 0; j < 8; j++) tm[j] = fmaxf(tm[j], __shfl_xor(tm[j], off, 64));
    if ((tid & 63) == 0) {
        const int bb = blockIdx.x >> 3;   // 512 rows per block, 4096 per b
#pragma unroll
        for (int j = 0; j < 8; j++) atomicMax(&Mmax[bb * 8 + j], fkey(tm[j]));
    }
}

// ---------------- pool: e=exp(t-M) on the fly, unnormalized wsum + Z --------
__global__ __launch_bounds__(256) void k_pool(
    const float* __restrict__ x, const float* __restrict__ t_in,
    const unsigned int* __restrict__ Mmax,
    float* __restrict__ pp, float* __restrict__ zp)
{
    __shared__ float ws_s[8][64];
    __shared__ float M_s[8];
    const int tid = threadIdx.x;
    const int oc = blockIdx.x;
    const int b  = blockIdx.y;
    if (tid < 8) {
        const unsigned int k = Mmax[b * 8 + tid];
        const unsigned int s = (k & 0x80000000u) ? (k & 0x7fffffffu) : ~k;
        M_s[tid] = __uint_as_float(s);
    }
    __syncthreads();
#pragma unroll
    for (int i = tid; i < 512; i += 256) {
        const int ol = i >> 3, hh = i & 7;
        const float tv = t_in[((size_t)b * O_ + oc * 64 + ol) * H_ + hh];
        ws_s[hh][ol] = __expf(tv - M_s[hh]);
    }
    __syncthreads();
    if (tid < 8) {
        float s = 0.f;
        for (int o = 0; o < 64; o++) s += ws_s[tid][o];
        zp[((size_t)oc * 32 + b) * 8 + tid] = s;
    }
    float acc[8];
#pragma unroll
    for (int hh = 0; hh < 8; hh++) acc[hh] = 0.f;
    const float* xp = x + ((size_t)b * O_ + oc * 64) * F_ + tid;
#pragma unroll 4
    for (int o = 0; o < 64; o++) {
        const float xv = xp[(size_t)o * F_];
#pragma unroll
        for (int hh = 0; hh < 8; hh++) acc[hh] += ws_s[hh][o] * xv;
    }
    float* outp = pp + ((size_t)oc * 32 + b) * 2048;
#pragma unroll
    for (int hh = 0; hh < 8; hh++) outp[hh * 256 + tid] = acc[hh];
}

// ---------------- reduce partials + divide by Z -----------------------------
__global__ __launch_bounds__(256) void k_reduce(
    const float* __restrict__ pp, const float* __restrict__ zp,
    float* __restrict__ out)
{
    const int blk = blockIdx.x;
    const int b = blk >> 3, hh = blk & 7;
    const int tid = threadIdx.x;
    __shared__ float invZ_s;
    if (tid < 64) {
        float z = zp[((size_t)tid * 32 + b) * 8 + hh];
#pragma unroll
        for (int off = 32; off; off >>= 1) z += __shfl_xor(z, off, 64);
        if (tid == 0) invZ_s = 1.f / z;
    }
    __syncthreads();
    float s = 0.f;
    const float* p0 = pp + (size_t)b * 2048 + hh * 256 + tid;
#pragma unroll 8
    for (int ocq = 0; ocq < 64; ocq++) s += p0[(size_t)ocq * 65536];
    out[(size_t)b * 2048 + hh * 256 + tid] = s * invZ_s;
}

extern "C" void kernel_launch(void* const* d_in, const int* in_sizes, int n_in,
                              void* d_out, int out_size, void* d_ws, size_t ws_size,
                              hipStream_t stream)
{
    const float* x      = (const float*)d_in[0];
    const float* gumbel = (const float*)d_in[1];
    const float* W_in   = (const float*)d_in[2];
    const float* b_in   = (const float*)d_in[3];
    const float* W_blk  = (const float*)d_in[4];
    const float* b_blk  = (const float*)d_in[5];
    const float* gamma  = (const float*)d_in[6];
    const float* beta   = (const float*)d_in[7];
    const float* W_fc   = (const float*)d_in[8];
    const float* b_fc   = (const float*)d_in[9];
    float* out = (float*)d_out;
    char* ws = (char*)d_ws;

    unsigned short* h_bf  = (unsigned short*)(ws + 0);            // 33554432
    float* pp     = (float*)(ws + 0);                              // 16777216 (alias)
    float* zp     = (float*)(ws + 16777216);                       // 65536    (alias)
    unsigned short* z_bf  = (unsigned short*)(ws + 33554432);      // 33554432
    float* mask   = (float*)(ws + 67108864);                       // 524288
    float* sumP   = (float*)(ws + 67633152);                       // 1048576 (2048x128)
    float* sumsqP = (float*)(ws + 68681728);                       // 1048576
    float* scale  = (float*)(ws + 69730304);                       // 512
    float* shift  = (float*)(ws + 69730816);                       // 512
    float* t_buf  = (float*)(ws + 69731328);                       // 4194304
    unsigned int* Mmax = (unsigned int*)(ws + 73925632);           // 1024
    unsigned short* WinT  = (unsigned short*)(ws + 73926656);      // 65536
    unsigned short* WblkT = (unsigned short*)(ws + 73992192);      // 32768

    k_prep<<<192, 256, 0, stream>>>(W_in, W_blk, WinT, WblkT, Mmax);
    k_fused<<<1024, 512, 0, stream>>>(x, WinT, b_in, WblkT, b_blk, h_bf, z_bf, mask, sumP, sumsqP);
    k_bnfin<<<128, 256, 0, stream>>>(sumP, sumsqP, gamma, beta, scale, shift);
    k_logits<<<256, 256, 0, stream>>>(h_bf, z_bf, scale, shift, W_fc, b_fc, mask, gumbel, t_buf, Mmax);
    k_pool<<<dim3(64, 32), 256, 0, stream>>>(x, t_buf, Mmax, pp, zp);
    k_reduce<<<256, 256, 0, stream>>>(pp, zp, out);
}

// Round 7
// 311.028 us; speedup vs baseline: 1.0590x; 1.0590x over previous
//
#include <hip/hip_runtime.h>
#include <math.h>

// Problem constants: B=32, O=4096, F=256, H=8, HID=128
#define MB_ 131072
#define F_  256
#define HID_ 128
#define H_  8
#define O_  4096
#define B_  32

typedef __attribute__((ext_vector_type(8))) short short8;
typedef __attribute__((ext_vector_type(4))) float f32x4;

static __device__ __forceinline__ unsigned short f2bf(float f) {
    unsigned int u = __float_as_uint(f);
    unsigned int r = (u + 0x7fffu + ((u >> 16) & 1u)) >> 16;  // RNE
    return (unsigned short)r;
}
static __device__ __forceinline__ float bflo(unsigned int u) {
    return __uint_as_float(u << 16);
}
static __device__ __forceinline__ float bfhi(unsigned int u) {
    return __uint_as_float(u & 0xffff0000u);
}
// order-preserving float->uint key for atomicMax
static __device__ __forceinline__ unsigned int fkey(float f) {
    unsigned int u = __float_as_uint(f);
    return (u & 0x80000000u) ? ~u : (u | 0x80000000u);
}
// pack 8 f32 (two float4) -> short8 bf16
static __device__ __forceinline__ short8 pack_bf16x8(const float4 a, const float4 b) {
    short8 r;
    r[0] = (short)f2bf(a.x); r[1] = (short)f2bf(a.y);
    r[2] = (short)f2bf(a.z); r[3] = (short)f2bf(a.w);
    r[4] = (short)f2bf(b.x); r[5] = (short)f2bf(b.y);
    r[6] = (short)f2bf(b.z); r[7] = (short)f2bf(b.w);
    return r;
}
// async 16B global->LDS copy (HW: wave-uniform LDS base + lane*16)
static __device__ __forceinline__ void gll16(const float* g, float* l) {
    __builtin_amdgcn_global_load_lds(
        (const __attribute__((address_space(1))) float*)g,
        (__attribute__((address_space(3))) float*)l, 16, 0, 0);
}

// ---------------- Prep: transpose + bf16-cast weights, init Mmax ------------
__global__ __launch_bounds__(256) void k_prep(
    const float* __restrict__ W_in, const float* __restrict__ W_blk,
    unsigned short* __restrict__ WinT, unsigned short* __restrict__ WblkT,
    unsigned int* __restrict__ Mmax)
{
    const int idx = blockIdx.x * 256 + threadIdx.x;
    if (idx < 256) Mmax[idx] = 0u;  // key-space -inf
    if (idx < 32768) {
        const int n = idx >> 8, k = idx & 255;
        WinT[idx] = f2bf(W_in[(size_t)k * HID_ + n]);
    } else {
        const int i2 = idx - 32768;  // < 16384
        const int n = i2 >> 7, k = i2 & 127;
        WblkT[i2] = f2bf(W_blk[(size_t)k * HID_ + n]);
    }
}

// ---------------- Fused GEMM1+GEMM2 -----------------------------------------
// GEMM1 (T3 2-phase template): x staged f32 via global_load_lds into
// stg[2][128][32] f32 (32 KB dbuf, source-side 16B-chunk XOR swizzle).
// Per K-step: bC(kt) loads -> STAGE(kt+1) -> ds_read f32 frags+cvt -> MFMA
// (counted vmcnt keeps stage flying) -> vmcnt(0)+barrier (once, after compute).
// GEMM2: A from h_s (32 KB bf16, unioned with stg), B frags from L2.
__global__ __launch_bounds__(512, 4) void k_fused(
    const float* __restrict__ x, const unsigned short* __restrict__ WinT,
    const float* __restrict__ b_in,
    const unsigned short* __restrict__ WblkT, const float* __restrict__ b_blk,
    unsigned short* __restrict__ h_out, unsigned short* __restrict__ z_out,
    float* __restrict__ mask_out,
    float* __restrict__ sumP, float* __restrict__ sumsqP)
{
    __shared__ unsigned short smem[16384];   // 32768 B
    float* stgf = (float*)smem;              // [2][128][32] f32, chunk-swizzled
    unsigned short* h_s = smem;              // [128][128] bf16 (after GEMM1)

    const int tid = threadIdx.x;
    const int R0 = blockIdx.x * 128;
    const int wave = tid >> 6;   // 0..7
    const int wrow = wave >> 2;  // 0..1
    const int wcol = wave & 3;   // 0..3
    const int lane = tid & 63;
    const int lm = lane & 15, quad = lane >> 4;

    // staging: wave covers physical rows 16w..16w+15 via 2 calls of 8 rows.
    // physical (r, cp) holds logical chunk cl = cp ^ (r&7)  (cp = lane&7)
    const int r0s = wave * 16 + (lane >> 3);
    const int r1s = r0s + 8;
    const int cl0 = (lane & 7) ^ (r0s & 7);
    const int cl1 = (lane & 7) ^ (r1s & 7);
    const float* g0 = x + (size_t)(R0 + r0s) * F_ + cl0 * 4;
    const float* g1 = x + (size_t)(R0 + r1s) * F_ + cl1 * 4;
    const int lbase = wave * 512;            // floats; call1 at +256

    // A-frag LDS float offsets (swizzled): row ar, chunks 2q, 2q+1
    int aoff[4][2];
#pragma unroll
    for (int mi = 0; mi < 4; mi++) {
        const int ar = wrow * 64 + mi * 16 + lm;
        aoff[mi][0] = ar * 32 + (((2 * quad) ^ (ar & 7)) << 2);
        aoff[mi][1] = ar * 32 + (((2 * quad + 1) ^ (ar & 7)) << 2);
    }
    // GEMM1 B-frag global pointers (WinT, L2-hot)
    const unsigned short* wr0 = WinT + (size_t)(wcol * 32 + lm) * F_ + quad * 8;
    const unsigned short* wr1 = wr0 + (size_t)16 * F_;

    f32x4 acc[4][2];
#pragma unroll
    for (int i = 0; i < 4; i++)
#pragma unroll
        for (int j = 0; j < 2; j++) acc[i][j] = (f32x4){0.f, 0.f, 0.f, 0.f};
    float msq[4] = {0.f, 0.f, 0.f, 0.f};

    // prologue: stage tile 0 into buffer 0
    gll16(g0, stgf + lbase);
    gll16(g1, stgf + lbase + 256);
    asm volatile("s_waitcnt vmcnt(0)" ::: "memory");
    __builtin_amdgcn_s_barrier();
    __builtin_amdgcn_sched_barrier(0);

    // ---- GEMM1: 8 K-steps of 32 (2-phase pipeline) ----
#pragma unroll
    for (int kt = 0; kt < 8; kt++) {
        const int b = kt & 1;
        // 1) B frags for kt — issued BEFORE stage(kt+1) so the compiler's
        //    wait on them (counted) does not drain the stage prefetch.
        const short8 bC0 = *(const short8*)(wr0 + kt * 32);
        const short8 bC1 = *(const short8*)(wr1 + kt * 32);
        // 2) stage kt+1 into the other buffer (async, flies across compute)
        if (kt < 7) {
            float* d = stgf + (b ^ 1) * 4096 + lbase;
            gll16(g0 + (kt + 1) * 32, d);
            gll16(g1 + (kt + 1) * 32, d + 256);
        }
        // 3) A frags from buffer b (f32) + mask sumsq + convert
        short8 af[4];
#pragma unroll
        for (int mi = 0; mi < 4; mi++) {
            const float4 fa = *(const float4*)(stgf + b * 4096 + aoff[mi][0]);
            const float4 fb = *(const float4*)(stgf + b * 4096 + aoff[mi][1]);
            if (wcol == 0)
                msq[mi] += fa.x * fa.x + fa.y * fa.y + fa.z * fa.z + fa.w * fa.w
                         + fb.x * fb.x + fb.y * fb.y + fb.z * fb.z + fb.w * fb.w;
            af[mi] = pack_bf16x8(fa, fb);
        }
        // 4) MFMA (compiler waits bC via counted vmcnt; stage keeps flying)
#pragma unroll
        for (int mi = 0; mi < 4; mi++) {
            acc[mi][0] = __builtin_amdgcn_mfma_f32_16x16x32_bf16(af[mi], bC0, acc[mi][0], 0, 0, 0);
            acc[mi][1] = __builtin_amdgcn_mfma_f32_16x16x32_bf16(af[mi], bC1, acc[mi][1], 0, 0, 0);
        }
        // 5) once-per-step drain AFTER compute: stage(kt+1) landed everywhere
        asm volatile("s_waitcnt vmcnt(0)" ::: "memory");
        __builtin_amdgcn_s_barrier();
        __builtin_amdgcn_sched_barrier(0);
    }

    // mask: wcol==0 waves cover all elements of their wrow-half rows
    if (wcol == 0) {
#pragma unroll
        for (int mi = 0; mi < 4; mi++) {
            float m = msq[mi];
            m += __shfl_xor(m, 16, 64);
            m += __shfl_xor(m, 32, 64);
            if (quad == 0)
                mask_out[R0 + wrow * 64 + mi * 16 + lm] = (m != 0.f) ? 1.f : 0.f;
        }
    }
    __syncthreads();   // all stg reads done before h_s overwrite

    // ---- epilogue 1: bias + relu -> h_s (swizzled) ----
    {
        float bcol[2];
#pragma unroll
        for (int ni = 0; ni < 2; ni++) bcol[ni] = b_in[wcol * 32 + ni * 16 + lm];
#pragma unroll
        for (int mi = 0; mi < 4; mi++)
#pragma unroll
            for (int r = 0; r < 4; r++) {
                const int rl = wrow * 64 + mi * 16 + quad * 4 + r;
#pragma unroll
                for (int ni = 0; ni < 2; ni++) {
                    const int col = wcol * 32 + ni * 16 + lm;
                    const float v = fmaxf(acc[mi][ni][r] + bcol[ni], 0.f);
                    h_s[rl * 128 + ((((col >> 3) ^ (rl & 7)) << 3) | (col & 7))] = f2bf(v);
                }
            }
    }
#pragma unroll
    for (int i = 0; i < 4; i++)
#pragma unroll
        for (int j = 0; j < 2; j++) acc[i][j] = (f32x4){0.f, 0.f, 0.f, 0.f};
    __syncthreads();   // h_s complete

    // ---- coalesced h_out stores from h_s (16B, fire-and-forget) ----
    {
        const int crow = tid >> 2, cb = tid & 3;
#pragma unroll
        for (int j = 0; j < 4; j++) {
            const int ch = cb * 4 + j;
            const short8 v = *(const short8*)(h_s + crow * 128 + ((ch ^ (crow & 7)) << 3));
            *(short8*)(h_out + (size_t)(R0 + crow) * HID_ + ch * 8) = v;
        }
    }

    // ---- GEMM2: A from h_s, B from WblkT (L2) ----
    {
        const unsigned short* wb0 = WblkT + (size_t)(wcol * 32 + lm) * HID_ + quad * 8;
        const unsigned short* wb1 = wb0 + (size_t)16 * HID_;
#pragma unroll
        for (int kt2 = 0; kt2 < 4; kt2++) {
            short8 wbf[2];
            wbf[0] = *(const short8*)(wb0 + kt2 * 32);
            wbf[1] = *(const short8*)(wb1 + kt2 * 32);
            short8 haf[4];
#pragma unroll
            for (int mi = 0; mi < 4; mi++) {
                const int hr = wrow * 64 + mi * 16 + lm;
                haf[mi] = *(const short8*)(h_s + hr * 128 + (((kt2 * 4 + quad) ^ (hr & 7)) << 3));
            }
#pragma unroll
            for (int mi = 0; mi < 4; mi++)
#pragma unroll
                for (int ni = 0; ni < 2; ni++)
                    acc[mi][ni] = __builtin_amdgcn_mfma_f32_16x16x32_bf16(haf[mi], wbf[ni], acc[mi][ni], 0, 0, 0);
        }
    }

    __syncthreads();   // all GEMM2 h_s reads done before z overwrite

    // ---- epilogue 2: bias, z -> h_s, BN partials via shfl ----
    {
        float bcol2[2];
#pragma unroll
        for (int ni = 0; ni < 2; ni++) bcol2[ni] = b_blk[wcol * 32 + ni * 16 + lm];
        float s_c[2] = {0.f, 0.f}, ss_c[2] = {0.f, 0.f};
#pragma unroll
        for (int mi = 0; mi < 4; mi++)
#pragma unroll
            for (int r = 0; r < 4; r++) {
                const int rl = wrow * 64 + mi * 16 + quad * 4 + r;
#pragma unroll
                for (int ni = 0; ni < 2; ni++) {
                    const int col = wcol * 32 + ni * 16 + lm;
                    const float zv = acc[mi][ni][r] + bcol2[ni];
                    s_c[ni] += zv;
                    ss_c[ni] += zv * zv;
                    h_s[rl * 128 + ((((col >> 3) ^ (rl & 7)) << 3) | (col & 7))] = f2bf(zv);
                }
            }
        // reduce over quad (rows) -> quad==0 lanes hold col sums for this wrow half
#pragma unroll
        for (int ni = 0; ni < 2; ni++) {
            s_c[ni]  += __shfl_xor(s_c[ni], 16, 64);
            s_c[ni]  += __shfl_xor(s_c[ni], 32, 64);
            ss_c[ni] += __shfl_xor(ss_c[ni], 16, 64);
            ss_c[ni] += __shfl_xor(ss_c[ni], 32, 64);
        }
        if (quad == 0) {
#pragma unroll
            for (int ni = 0; ni < 2; ni++) {
                const int col = wcol * 32 + ni * 16 + lm;
                sumP[((size_t)blockIdx.x * 2 + wrow) * 128 + col]   = s_c[ni];
                sumsqP[((size_t)blockIdx.x * 2 + wrow) * 128 + col] = ss_c[ni];
            }
        }
    }
    __syncthreads();   // z tile complete

    // ---- coalesced z_out stores ----
    {
        const int crow = tid >> 2, cb = tid & 3;
#pragma unroll
        for (int j = 0; j < 4; j++) {
            const int ch = cb * 4 + j;
            const short8 v = *(const short8*)(h_s + crow * 128 + ((ch ^ (crow & 7)) << 3));
            *(short8*)(z_out + (size_t)(R0 + crow) * HID_ + ch * 8) = v;
        }
    }
}

// ---------------- BN finalize (2048 partials) -------------------------------
__global__ __launch_bounds__(256) void k_bnfin(
    const float* __restrict__ sumP, const float* __restrict__ sumsqP,
    const float* __restrict__ gamma, const float* __restrict__ beta,
    float* __restrict__ scale, float* __restrict__ shift)
{
    const int c = blockIdx.x;
    const int tid = threadIdx.x;
    float s = 0.f, ss = 0.f;
    for (int i = tid; i < 2048; i += 256) {
        s  += sumP[(size_t)i * 128 + c];
        ss += sumsqP[(size_t)i * 128 + c];
    }
#pragma unroll
    for (int off = 32; off; off >>= 1) {
        s  += __shfl_xor(s, off, 64);
        ss += __shfl_xor(ss, off, 64);
    }
    __shared__ float rs[4], rss[4];
    const int wid = tid >> 6, lane = tid & 63;
    if (lane == 0) { rs[wid] = s; rss[wid] = ss; }
    __syncthreads();
    if (tid == 0) {
        const float S  = rs[0] + rs[1] + rs[2] + rs[3];
        const float SS = rss[0] + rss[1] + rss[2] + rss[3];
        const float inv_m = 1.0f / (float)MB_;
        const float mu = S * inv_m;
        const float var = SS * inv_m - mu * mu;
        const float sc = gamma[c] * rsqrtf(var + 1e-5f);
        scale[c] = sc;
        shift[c] = beta[c] - mu * sc;
    }
}

// ---------------- logits + gumbel + per-(b,h) max ---------------------------
__global__ __launch_bounds__(256) void k_logits(
    const unsigned short* __restrict__ h_in, const unsigned short* __restrict__ z_in,
    const float* __restrict__ scale, const float* __restrict__ shift,
    const float* __restrict__ W_fc, const float* __restrict__ b_fc,
    const float* __restrict__ mask, const float* __restrict__ gumbel,
    float* __restrict__ t_out, unsigned int* __restrict__ Mmax)
{
    __shared__ float wfc_s[1024];
    __shared__ float sc_s[128], sh_s[128];
    const int tid = threadIdx.x;
    for (int i = tid; i < 1024; i += 256) wfc_s[i] = W_fc[i];
    if (tid < 128) { sc_s[tid] = scale[tid]; sh_s[tid] = shift[tid]; }
    __syncthreads();

    const size_t row0 = (size_t)blockIdx.x * 512 + tid;
    const size_t row1 = row0 + 256;
    float a0[8], a1[8];
#pragma unroll
    for (int j = 0; j < 8; j++) { a0[j] = 0.f; a1[j] = 0.f; }

    const uint4* hp0 = (const uint4*)(h_in + row0 * HID_);
    const uint4* zq0 = (const uint4*)(z_in + row0 * HID_);
    const uint4* hp1 = (const uint4*)(h_in + row1 * HID_);
    const uint4* zq1 = (const uint4*)(z_in + row1 * HID_);

#pragma unroll 2
    for (int kc = 0; kc < 16; kc++) {
        const uint4 h0 = hp0[kc], z0 = zq0[kc];
        const uint4 h1 = hp1[kc], z1 = zq1[kc];
        const unsigned int hs0[4] = {h0.x, h0.y, h0.z, h0.w};
        const unsigned int zs0[4] = {z0.x, z0.y, z0.z, z0.w};
        const unsigned int hs1[4] = {h1.x, h1.y, h1.z, h1.w};
        const unsigned int zs1[4] = {z1.x, z1.y, z1.z, z1.w};
#pragma unroll
        for (int p = 0; p < 4; p++) {
            const int k = kc * 8 + p * 2;
            const float sck0 = sc_s[k], shk0 = sh_s[k];
            const float sck1 = sc_s[k + 1], shk1 = sh_s[k + 1];
            const float4 wA = *(const float4*)&wfc_s[k * 8];
            const float4 wB = *(const float4*)&wfc_s[k * 8 + 4];
            const float4 wC = *(const float4*)&wfc_s[k * 8 + 8];
            const float4 wD = *(const float4*)&wfc_s[k * 8 + 12];
            {
                const float hf0 = bflo(hs0[p]), hf1 = bfhi(hs0[p]);
                const float zf0 = bflo(zs0[p]), zf1 = bfhi(zs0[p]);
                const float hb0 = fmaxf(zf0 * sck0 + shk0, 0.f) + hf0;
                const float hb1 = fmaxf(zf1 * sck1 + shk1, 0.f) + hf1;
                a0[0] += hb0 * wA.x + hb1 * wC.x;  a0[1] += hb0 * wA.y + hb1 * wC.y;
                a0[2] += hb0 * wA.z + hb1 * wC.z;  a0[3] += hb0 * wA.w + hb1 * wC.w;
                a0[4] += hb0 * wB.x + hb1 * wD.x;  a0[5] += hb0 * wB.y + hb1 * wD.y;
                a0[6] += hb0 * wB.z + hb1 * wD.z;  a0[7] += hb0 * wB.w + hb1 * wD.w;
            }
            {
                const float hf0 = bflo(hs1[p]), hf1 = bfhi(hs1[p]);
                const float zf0 = bflo(zs1[p]), zf1 = bfhi(zs1[p]);
                const float hb0 = fmaxf(zf0 * sck0 + shk0, 0.f) + hf0;
                const float hb1 = fmaxf(zf1 * sck1 + shk1, 0.f) + hf1;
                a1[0] += hb0 * wA.x + hb1 * wC.x;  a1[1] += hb0 * wA.y + hb1 * wC.y;
                a1[2] += hb0 * wA.z + hb1 * wC.z;  a1[3] += hb0 * wA.w + hb1 * wC.w;
                a1[4] += hb0 * wB.x + hb1 * wD.x;  a1[5] += hb0 * wB.y + hb1 * wD.y;
                a1[6] += hb0 * wB.z + hb1 * wD.z;  a1[7] += hb0 * wB.w + hb1 * wD.w;
            }
        }
    }

    float bf[8];
#pragma unroll
    for (int j = 0; j < 8; j++) bf[j] = b_fc[j];
    const float mk0 = mask[row0], mk1 = mask[row1];
    float g0[8], g1[8];
    *(float4*)&g0[0] = *(const float4*)(gumbel + row0 * 8);
    *(float4*)&g0[4] = *(const float4*)(gumbel + row0 * 8 + 4);
    *(float4*)&g1[0] = *(const float4*)(gumbel + row1 * 8);
    *(float4*)&g1[4] = *(const float4*)(gumbel + row1 * 8 + 4);
    float t0[8], t1[8];
#pragma unroll
    for (int j = 0; j < 8; j++) {
        t0[j] = (a0[j] + bf[j]) * mk0 + g0[j];
        t1[j] = (a1[j] + bf[j]) * mk1 + g1[j];
    }
    *(float4*)(t_out + row0 * 8)     = *(float4*)&t0[0];
    *(float4*)(t_out + row0 * 8 + 4) = *(float4*)&t0[4];
    *(float4*)(t_out + row1 * 8)     = *(float4*)&t1[0];
    *(float4*)(t_out + row1 * 8 + 4) = *(float4*)&t1[4];

    float tm[8];
#pragma unroll
    for (int j = 0; j < 8; j++) tm[j] = fmaxf(t0[j], t1[j]);
#pragma unroll
    for (int off = 32; off; off >>= 1)
#pragma unroll
        for (int j = 0; j < 8; j++) tm[j] = fmaxf(tm[j], __shfl_xor(tm[j], off, 64));
    if ((tid & 63) == 0) {
        const int bb = blockIdx.x >> 3;   // 512 rows per block, 4096 per b
#pragma unroll
        for (int j = 0; j < 8; j++) atomicMax(&Mmax[bb * 8 + j], fkey(tm[j]));
    }
}

// ---------------- pool: e=exp(t-M) on the fly, unnormalized wsum + Z --------
__global__ __launch_bounds__(256) void k_pool(
    const float* __restrict__ x, const float* __restrict__ t_in,
    const unsigned int* __restrict__ Mmax,
    float* __restrict__ pp, float* __restrict__ zp)
{
    __shared__ float ws_s[8][64];
    __shared__ float M_s[8];
    const int tid = threadIdx.x;
    const int oc = blockIdx.x;
    const int b  = blockIdx.y;
    if (tid < 8) {
        const unsigned int k = Mmax[b * 8 + tid];
        const unsigned int s = (k & 0x80000000u) ? (k & 0x7fffffffu) : ~k;
        M_s[tid] = __uint_as_float(s);
    }
    __syncthreads();
#pragma unroll
    for (int i = tid; i < 512; i += 256) {
        const int ol = i >> 3, hh = i & 7;
        const float tv = t_in[((size_t)b * O_ + oc * 64 + ol) * H_ + hh];
        ws_s[hh][ol] = __expf(tv - M_s[hh]);
    }
    __syncthreads();
    if (tid < 8) {
        float s = 0.f;
        for (int o = 0; o < 64; o++) s += ws_s[tid][o];
        zp[((size_t)oc * 32 + b) * 8 + tid] = s;
    }
    float acc[8];
#pragma unroll
    for (int hh = 0; hh < 8; hh++) acc[hh] = 0.f;
    const float* xp = x + ((size_t)b * O_ + oc * 64) * F_ + tid;
#pragma unroll 4
    for (int o = 0; o < 64; o++) {
        const float xv = xp[(size_t)o * F_];
#pragma unroll
        for (int hh = 0; hh < 8; hh++) acc[hh] += ws_s[hh][o] * xv;
    }
    float* outp = pp + ((size_t)oc * 32 + b) * 2048;
#pragma unroll
    for (int hh = 0; hh < 8; hh++) outp[hh * 256 + tid] = acc[hh];
}

// ---------------- reduce partials + divide by Z -----------------------------
__global__ __launch_bounds__(256) void k_reduce(
    const float* __restrict__ pp, const float* __restrict__ zp,
    float* __restrict__ out)
{
    const int blk = blockIdx.x;
    const int b = blk >> 3, hh = blk & 7;
    const int tid = threadIdx.x;
    __shared__ float invZ_s;
    if (tid < 64) {
        float z = zp[((size_t)tid * 32 + b) * 8 + hh];
#pragma unroll
        for (int off = 32; off; off >>= 1) z += __shfl_xor(z, off, 64);
        if (tid == 0) invZ_s = 1.f / z;
    }
    __syncthreads();
    float s = 0.f;
    const float* p0 = pp + (size_t)b * 2048 + hh * 256 + tid;
#pragma unroll 8
    for (int ocq = 0; ocq < 64; ocq++) s += p0[(size_t)ocq * 65536];
    out[(size_t)b * 2048 + hh * 256 + tid] = s * invZ_s;
}

extern "C" void kernel_launch(void* const* d_in, const int* in_sizes, int n_in,
                              void* d_out, int out_size, void* d_ws, size_t ws_size,
                              hipStream_t stream)
{
    const float* x      = (const float*)d_in[0];
    const float* gumbel = (const float*)d_in[1];
    const float* W_in   = (const float*)d_in[2];
    const float* b_in   = (const float*)d_in[3];
    const float* W_blk  = (const float*)d_in[4];
    const float* b_blk  = (const float*)d_in[5];
    const float* gamma  = (const float*)d_in[6];
    const float* beta   = (const float*)d_in[7];
    const float* W_fc   = (const float*)d_in[8];
    const float* b_fc   = (const float*)d_in[9];
    float* out = (float*)d_out;
    char* ws = (char*)d_ws;

    unsigned short* h_bf  = (unsigned short*)(ws + 0);            // 33554432
    float* pp     = (float*)(ws + 0);                              // 16777216 (alias)
    float* zp     = (float*)(ws + 16777216);                       // 65536    (alias)
    unsigned short* z_bf  = (unsigned short*)(ws + 33554432);      // 33554432
    float* mask   = (float*)(ws + 67108864);                       // 524288
    float* sumP   = (float*)(ws + 67633152);                       // 1048576 (2048x128)
    float* sumsqP = (float*)(ws + 68681728);                       // 1048576
    float* scale  = (float*)(ws + 69730304);                       // 512
    float* shift  = (float*)(ws + 69730816);                       // 512
    float* t_buf  = (float*)(ws + 69731328);                       // 4194304
    unsigned int* Mmax = (unsigned int*)(ws + 73925632);           // 1024
    unsigned short* WinT  = (unsigned short*)(ws + 73926656);      // 65536
    unsigned short* WblkT = (unsigned short*)(ws + 73992192);      // 32768

    k_prep<<<192, 256, 0, stream>>>(W_in, W_blk, WinT, WblkT, Mmax);
    k_fused<<<1024, 512, 0, stream>>>(x, WinT, b_in, WblkT, b_blk, h_bf, z_bf, mask, sumP, sumsqP);
    k_bnfin<<<128, 256, 0, stream>>>(sumP, sumsqP, gamma, beta, scale, shift);
    k_logits<<<256, 256, 0, stream>>>(h_bf, z_bf, scale, shift, W_fc, b_fc, mask, gumbel, t_buf, Mmax);
    k_pool<<<dim3(64, 32), 256, 0, stream>>>(x, t_buf, Mmax, pp, zp);
    k_reduce<<<256, 256, 0, stream>>>(pp, zp, out);
}